// Round 8
// baseline (634.322 us; speedup 1.0000x reference)
//
#include <hip/hip_runtime.h>
#include <hip/hip_bf16.h>

// GraphLayer B=8,N=2048,D=512 — Round 12.
//   r11 post-mortem: race fixed (passed, conflicts 0) but 233->224us only.
//   Still latency-bound: 576 barrier-steps x ~930cy for ~2 MFMAs each; the
//   per-step chain (wait->bar->ds_read->2 MFMA) can't pipeline across
//   sched_barrier(0) regions; NT adj loads (~900cy) sit on the serial
//   epilogue path.
//   Changes (attn only; math bit-identical to r9/r11):
//   1) Chunk 128 (16KB): 8 steps/tile x 4 MFMAs; barriers 18->9 per tile.
//   2) 3 rotating buffers, POST-barrier stage issue, depth 2: stage chunk
//      g+2 after BAR of step g -> target buf last read at step g-1, reads
//      drained by lgkmcnt(0) before this BAR => WAR-safe. Counted waits:
//      vmcnt(2) except vmcnt(3) at P2S1/P2S2 (adj instr in the count).
//   3) adj tile staged to LDS one tile ahead (issued P2S0) — epilogue adj
//      reads now LDS-local (T14); NT global adj loads deleted.
//   4) s_setprio(1) around MFMA clusters (T5; schedule now role-diverse).
//   LDS 60.5KB static (3x16 Bf + 4 Pb + 8 sAdj + 0.5 denL), 2 blocks/CU.
// Numerics identical to r9/r11 (passed, absmax 0.0156): same operand values,
// same accumulation order; fp16 Q/K, P/V bf16, fp32 accum, den = fp32 sum
// of the SAME bf16-rounded P.

#define BATCH 8
#define SEQ   2048
#define DIM   512
#define MSEQ  (BATCH * SEQ)   // 16384
#define QB    32              // q-rows per attn block
#define KT    64              // k-tile width
#define NTI   (SEQ / KT)      // 32 k-tiles
#define CHK   128             // D-cols per K chunk / d-rows per V chunk

typedef __attribute__((ext_vector_type(8))) short    bf16x8;
typedef __attribute__((ext_vector_type(8))) _Float16 f16x8;
typedef __attribute__((ext_vector_type(4))) float    f32x4;

__device__ __forceinline__ unsigned short f2bf(float f) {
  __hip_bfloat16 h = __float2bfloat16(f);
  union { __hip_bfloat16 h; unsigned short u; } c; c.h = h; return c.u;
}
__device__ __forceinline__ float bf2f(unsigned short u) {
  union { unsigned int u; float f; } c; c.u = ((unsigned int)u) << 16; return c.f;
}
__device__ __forceinline__ unsigned short f2h(float f) {
  union { _Float16 h; unsigned short u; } c; c.h = (_Float16)f; return c.u;
}

__device__ __forceinline__ void async16(const unsigned short* g, unsigned short* l) {
  __builtin_amdgcn_global_load_lds(
      (const __attribute__((address_space(1))) void*)g,
      (__attribute__((address_space(3))) void*)l, 16, 0, 0);
}

#define WAIT2() asm volatile("s_waitcnt vmcnt(2) lgkmcnt(0)" ::: "memory")
#define WAIT3() asm volatile("s_waitcnt vmcnt(3) lgkmcnt(0)" ::: "memory")
#define WAIT_LGKM0() asm volatile("s_waitcnt lgkmcnt(0)" ::: "memory")
// barrier with ACQUIRE fence: post-barrier LDS ops cannot hoist above
#define BAR_ACQ()                                                  \
  do {                                                             \
    __builtin_amdgcn_s_barrier();                                  \
    asm volatile("" ::: "memory");                                 \
    __builtin_amdgcn_sched_barrier(0);                             \
  } while (0)

// ---------------------------------------------------------------- core ----
// acc[i][j] += A[m][k] * B[n][k]  (NT), fp16 MFMA, fp32 acc. 256 threads.
__device__ __forceinline__ void gemm_f16_mainloop(
    const unsigned short* __restrict__ A, const unsigned short* __restrict__ B,
    int lda, int ldb, int K,
    unsigned short* sA, unsigned short* sB, f32x4 acc[4][4])
{
  const int tid  = threadIdx.x;
  const int lane = tid & 63;
  const int w    = tid >> 6;
  const int wm   = w >> 1, wn = w & 1;
  const int quad = lane >> 4, fcol = lane & 15;
  const int srow = lane >> 2;          // 0..15 within a 16-row chunk
  const int gsw  = ((lane & 3) ^ ((srow & 3) ^ ((srow >> 2) & 3))) * 8;
  const int grd  = ((fcol & 3) ^ ((fcol >> 2) & 3));

  for (int k0 = 0; k0 < K; k0 += 32) {
#pragma unroll
    for (int inst = 0; inst < 2; ++inst) {
      const int rbase  = w * 32 + inst * 16;   // wave-uniform
      const int r      = rbase + srow;
      const int ldsoff = rbase * 32;           // row stride 32 ushorts
      async16(A + (size_t)r * lda + k0 + gsw, sA + ldsoff);
      async16(B + (size_t)r * ldb + k0 + gsw, sB + ldsoff);
    }
    __syncthreads();

#pragma unroll
    for (int i = 0; i < 4; ++i) {
      const int ar = wm * 64 + i * 16 + fcol;
      f16x8 a = *(const f16x8*)(sA + ar * 32 + ((quad ^ grd) << 3));
#pragma unroll
      for (int j = 0; j < 4; ++j) {
        const int br = wn * 64 + j * 16 + fcol;
        f16x8 b = *(const f16x8*)(sB + br * 32 + ((quad ^ grd) << 3));
        acc[i][j] = __builtin_amdgcn_mfma_f32_16x16x32_f16(a, b, acc[i][j], 0, 0, 0);
      }
    }
    __syncthreads();
  }
}

#define EPI_SETUP                                                  \
  const int lane = threadIdx.x & 63;                               \
  const int w_   = threadIdx.x >> 6;                               \
  const int wm   = w_ >> 1, wn = w_ & 1;                           \
  const int quad = lane >> 4, fcol = lane & 15;

// ----------------------------------------------------------------- cvt ----
__global__ __launch_bounds__(256) void cvt_kernel(
    const float* __restrict__ in, unsigned short* __restrict__ out, int n4)
{
  int i = blockIdx.x * 256 + threadIdx.x;
  if (i >= n4) return;
  float4 v = ((const float4*)in)[i];
  ushort4 h;
  h.x = f2h(v.x); h.y = f2h(v.y); h.z = f2h(v.z); h.w = f2h(v.w);
  ((ushort4*)out)[i] = h;
}

__global__ __launch_bounds__(256) void cvt_w_kernel(
    const float* __restrict__ w0, const float* __restrict__ w1,
    const float* __restrict__ w2, unsigned short* __restrict__ o0,
    unsigned short* __restrict__ o1, unsigned short* __restrict__ o2, int n4)
{
  int i = blockIdx.x * 256 + threadIdx.x;
  if (i >= n4) return;
  const float* in = (blockIdx.y == 0) ? w0 : (blockIdx.y == 1) ? w1 : w2;
  unsigned short* out = (blockIdx.y == 0) ? o0 : (blockIdx.y == 1) ? o1 : o2;
  float4 v = ((const float4*)in)[i];
  ushort4 h;
  h.x = f2h(v.x); h.y = f2h(v.y); h.z = f2h(v.z); h.w = f2h(v.w);
  ((ushort4*)out)[i] = h;
}

// ------------------------------------------------------------- proj QK ----
__global__ __launch_bounds__(256) void proj_qk_kernel(
    const unsigned short* __restrict__ xh,
    const unsigned short* __restrict__ wq, const unsigned short* __restrict__ wk,
    const float* __restrict__ bq, const float* __restrict__ bk,
    unsigned short* __restrict__ Qh, unsigned short* __restrict__ Kh)
{
  __shared__ unsigned short sA[128 * 32], sB[128 * 32];
  const unsigned short* wh = blockIdx.z ? wk : wq;
  const float* bias        = blockIdx.z ? bk : bq;
  unsigned short* O        = blockIdx.z ? Kh : Qh;
  const int m0 = blockIdx.y * 128, n0 = blockIdx.x * 128;
  f32x4 acc[4][4];
#pragma unroll
  for (int i = 0; i < 4; ++i)
#pragma unroll
    for (int j = 0; j < 4; ++j) acc[i][j] = (f32x4){0.f, 0.f, 0.f, 0.f};

  gemm_f16_mainloop(xh + (size_t)m0 * DIM, wh + (size_t)n0 * DIM,
                    DIM, DIM, DIM, sA, sB, acc);
  EPI_SETUP
#pragma unroll
  for (int i = 0; i < 4; ++i)
#pragma unroll
    for (int j = 0; j < 4; ++j)
#pragma unroll
      for (int r = 0; r < 4; ++r) {
        const int row = m0 + wm * 64 + i * 16 + quad * 4 + r;
        const int col = n0 + wn * 64 + j * 16 + fcol;
        O[(size_t)row * DIM + col] = f2h(acc[i][j][r] + bias[col]);
      }
}

// -------------------------------------------------------------- proj V ----
// Vt[d][m] = Wv[d][:] . x[m][:] + bv[d]   (fp16 in, bf16 out, transposed)
__global__ __launch_bounds__(256) void proj_v_kernel(
    const unsigned short* __restrict__ wvh, const unsigned short* __restrict__ xh,
    const float* __restrict__ bias, unsigned short* __restrict__ Vt)
{
  __shared__ unsigned short sA[128 * 32], sB[128 * 32];
  const int m0 = blockIdx.y * 128, n0 = blockIdx.x * 128;
  f32x4 acc[4][4];
#pragma unroll
  for (int i = 0; i < 4; ++i)
#pragma unroll
    for (int j = 0; j < 4; ++j) acc[i][j] = (f32x4){0.f, 0.f, 0.f, 0.f};

  gemm_f16_mainloop(wvh + (size_t)m0 * DIM, xh + (size_t)n0 * DIM,
                    DIM, DIM, DIM, sA, sB, acc);
  EPI_SETUP
#pragma unroll
  for (int i = 0; i < 4; ++i)
#pragma unroll
    for (int j = 0; j < 4; ++j)
#pragma unroll
      for (int r = 0; r < 4; ++r) {
        const int row = m0 + wm * 64 + i * 16 + quad * 4 + r;   // d
        const int col = n0 + wn * 64 + j * 16 + fcol;           // seq
        Vt[(size_t)row * MSEQ + col] = f2bf(acc[i][j][r] + bias[row]);
      }
}

// ---------------------------------------------------------------- attn ----
// Fused scores+agg; 3-buffer rotating chunk pipeline (depth 2, post-barrier
// stage issue); Q in registers; adj pre-staged to LDS; setprio on MFMA.
// Block: 32 q-rows x D=512, 512 threads (8 waves), 2 blocks/CU.
__global__ __launch_bounds__(512, 4) void attn_kernel(
    const unsigned short* __restrict__ Qh, const unsigned short* __restrict__ Kh,
    const unsigned short* __restrict__ Vt, const float* __restrict__ adj,
    float* __restrict__ out)
{
  // LDS 61952B: Bf[3][8192]us (48KB) | Pb[32][64]us (4KB)
  //           | sAdj[32][64]f32 (8KB) | denL[4][32]f32 (512B)
  __shared__ __align__(16) unsigned short smem[30976];
  unsigned short* Bf    = smem;                    // 3 x 8192 ushorts
  unsigned short* Pb    = smem + 24576;            // row stride 64 ushorts
  unsigned short* sAdjU = smem + 26624;            // 4096 ushorts = 8KB
  float*          sAdjF = (float*)sAdjU;           // [32][64]
  float*          denL  = (float*)(smem + 30720);  // [4][32]

  const int tid  = threadIdx.x;
  const int lane = tid & 63;
  const int w    = tid >> 6;                    // 0..7
  const int quad = lane >> 4, fcol = lane & 15;
  const int wq = w >> 2, wk = w & 3;            // phase-1 grid 2q x 4k (16x16)
  const int dsub = w >> 1, qsub = w & 1;        // phase-2 grid 4d x 2q (16x16)

  // XCD affinity: round-robin dispatch -> lin%8 = XCD; batch b lives there.
  const int lin = blockIdx.x;                   // 0..511
  const int b   = lin & 7;
  const int q0  = (lin >> 3) * QB;
  const size_t qbase = (size_t)b * SEQ + q0;
  const size_t kbb   = (size_t)b * SEQ;
  const float* adjb  = adj + qbase * SEQ;

  // ---- staging (LDS bases wave-uniform; per-lane global src swizzled)
  // K chunk: [64 k-rows][128 D] fp16 = 16KB; 16 granules/row, XOR row&15.
  auto stage_k = [&](int t, int c, unsigned short* buf) {
#pragma unroll
    for (int rr = 0; rr < 2; ++rr) {
      const int gp  = rr * 512 + tid;
      const int row = gp >> 4, g = gp & 15;
      async16(Kh + (kbb + (size_t)t * KT + row) * DIM + c * CHK + ((g ^ (row & 15)) << 3),
              buf + rr * 4096 + w * 512);
    }
  };
  // V chunk: [128 d-rows][64 k] bf16 = 16KB; 8 granules/row, XOR row&7.
  auto stage_v = [&](int t, int c, unsigned short* buf) {
#pragma unroll
    for (int rr = 0; rr < 2; ++rr) {
      const int gp  = rr * 512 + tid;
      const int row = gp >> 3, g = gp & 7;
      async16(Vt + (size_t)(c * CHK + row) * MSEQ + kbb + (size_t)t * KT + ((g ^ (row & 7)) << 3),
              buf + rr * 4096 + w * 512);
    }
  };
  // adj tile: [32 rows][64 cols] f32 = 8KB, linear (scalar epilogue reads).
  auto stage_adj = [&](int t) {
    const int row = tid >> 4, g = tid & 15;
    async16((const unsigned short*)(adjb + (size_t)row * SEQ + (size_t)t * KT + g * 4),
            sAdjU + w * 512);
  };

  // ---- Q fragments -> registers (one-time; row = wq*16+fcol, 16 D-slices)
  const int arq = wq * 16 + fcol;
  f16x8 qf[16];
#pragma unroll
  for (int i = 0; i < 16; ++i)
    qf[i] = *(const f16x8*)(Qh + (qbase + arq) * DIM + i * 32 + quad * 8);

  f32x4 acc[8];                                 // out^T: one 16x16 per d-block
#pragma unroll
  for (int c = 0; c < 8; ++c) acc[c] = (f32x4){0.f, 0.f, 0.f, 0.f};
  float den[4] = {0.f, 0.f, 0.f, 0.f};

  // rotating buffers: chunk g (continuous counter) lives in p[(g+2t)%3];
  // rotation at tile end keeps local mapping chunk0->p0,1->p1,2->p2,...
  unsigned short* p0 = Bf;
  unsigned short* p1 = Bf + 8192;
  unsigned short* p2 = Bf + 16384;

  // prologue: adj(0) oldest, then K chunks 0,1
  stage_adj(0);
  stage_k(0, 0, p0);
  stage_k(0, 1, p1);

  const int br = wk * 16 + fcol;                // phase-1 K row
  const int vr0 = dsub * 16 + fcol;             // phase-2 V rows
  const int vr1 = 64 + dsub * 16 + fcol;
  const int qr  = qsub * 16 + fcol;             // phase-2 P q-row

  for (int t = 0; t < NTI; ++t) {
    const int tn = (t + 1 < NTI) ? t + 1 : 0;
    f32x4 sacc = (f32x4){0.f, 0.f, 0.f, 0.f};

    // ---- phase 1: S[32x64] = Q.K^T, 4 steps x 4 MFMAs ------------------
#pragma unroll
    for (int c = 0; c < 4; ++c) {
      WAIT2();
      BAR_ACQ();
      // stage chunk c+2 into p[(c+2)%3]; c=0:K2->p2 1:K3->p0 2:V0->p1 3:V1->p2
      if      (c == 0) stage_k(t, 2, p2);
      else if (c == 1) stage_k(t, 3, p0);
      else if (c == 2) stage_v(t, 0, p1);
      else             stage_v(t, 1, p2);
      const unsigned short* Kb = (c == 0) ? p0 : (c == 1) ? p1 : (c == 2) ? p2 : p0;
      __builtin_amdgcn_s_setprio(1);
#pragma unroll
      for (int kw = 0; kw < 4; ++kw) {
        const int G = kw * 4 + quad;
        f16x8 bb = *(const f16x8*)(Kb + br * 128 + ((G ^ (br & 15)) << 3));
        sacc = __builtin_amdgcn_mfma_f32_16x16x32_f16(qf[c * 4 + kw], bb, sacc, 0, 0, 0);
      }
      __builtin_amdgcn_s_setprio(0);
    }

    // ---- epilogue: P = bf16(adj*exp(S)) -> Pb; den += P (adj from LDS) --
    {
      const int col = wk * 16 + fcol;
#pragma unroll
      for (int r = 0; r < 4; ++r) {
        const int row = wq * 16 + quad * 4 + r;
        const float aval = sAdjF[row * 64 + col];
        const unsigned short pb = f2bf(aval * __expf(sacc[r]));
        Pb[row * 64 + ((((col >> 3) ^ (row & 7)) << 3) | (col & 7))] = pb;
        den[r] += bf2f(pb);
      }
    }
    WAIT_LGKM0();          // my sAdj reads + P writes retired
    BAR_ACQ();             // all P visible; in-flight DMAs unaffected

    // pa-cache: P fragments once per tile (k-windows 0,1)
    bf16x8 pa0 = *(const bf16x8*)(Pb + qr * 64 + ((quad ^ (qr & 7)) << 3));
    bf16x8 pa1 = *(const bf16x8*)(Pb + qr * 64 + (((4 + quad) ^ (qr & 7)) << 3));

    // ---- phase 2: accT += V.P^T, 4 steps x 4 MFMAs ---------------------
#pragma unroll
    for (int c = 0; c < 4; ++c) {
      if (c == 1 || c == 2) { WAIT3(); } else { WAIT2(); }
      BAR_ACQ();
      // stage chunk g+2: c=0: V2->p0 (+adj(t+1)); 1: V3->p1; 2: K'(0)->p2;
      //                  3: K'(1)->p0
      if      (c == 0) { stage_v(t, 2, p0); stage_adj(tn); }
      else if (c == 1) stage_v(t, 3, p1);
      else if (c == 2) stage_k(tn, 0, p2);
      else             stage_k(tn, 1, p0);
      const unsigned short* Vb = (c == 0) ? p1 : (c == 1) ? p2 : (c == 2) ? p0 : p1;
      bf16x8 va00 = *(const bf16x8*)(Vb + vr0 * 64 + ((quad ^ (vr0 & 7)) << 3));
      bf16x8 va01 = *(const bf16x8*)(Vb + vr0 * 64 + (((4 + quad) ^ (vr0 & 7)) << 3));
      bf16x8 va10 = *(const bf16x8*)(Vb + vr1 * 64 + ((quad ^ (vr1 & 7)) << 3));
      bf16x8 va11 = *(const bf16x8*)(Vb + vr1 * 64 + (((4 + quad) ^ (vr1 & 7)) << 3));
      __builtin_amdgcn_s_setprio(1);
      acc[2 * c]     = __builtin_amdgcn_mfma_f32_16x16x32_bf16(va00, pa0, acc[2 * c], 0, 0, 0);
      acc[2 * c]     = __builtin_amdgcn_mfma_f32_16x16x32_bf16(va01, pa1, acc[2 * c], 0, 0, 0);
      acc[2 * c + 1] = __builtin_amdgcn_mfma_f32_16x16x32_bf16(va10, pa0, acc[2 * c + 1], 0, 0, 0);
      acc[2 * c + 1] = __builtin_amdgcn_mfma_f32_16x16x32_bf16(va11, pa1, acc[2 * c + 1], 0, 0, 0);
      __builtin_amdgcn_s_setprio(0);
    }

    // rotate buffer pointers: chunk counter advances 8 (mod 3 -> +2)
    { unsigned short* tp = p0; p0 = p2; p2 = p1; p1 = tp; }
  }

  // ----------------- den reduce + normalize + store -------------------
#pragma unroll
  for (int r = 0; r < 4; ++r) {
    float v = den[r];
    v += __shfl_xor(v, 1);  v += __shfl_xor(v, 2);
    v += __shfl_xor(v, 4);  v += __shfl_xor(v, 8);
    if (fcol == 0) denL[wk * 32 + wq * 16 + quad * 4 + r] = v;
  }
  __syncthreads();   // full drain + fence fine at kernel end
  const int qloc = qsub * 16 + fcol;
  const float dsum = denL[qloc] + denL[32 + qloc] + denL[64 + qloc] + denL[96 + qloc];
  const float rd = 1.0f / dsum;
  float* orow = out + (qbase + qloc) * DIM + dsub * 16 + quad * 4;
#pragma unroll
  for (int c = 0; c < 8; ++c) {
    f32x4 o = {acc[c][0] * rd, acc[c][1] * rd, acc[c][2] * rd, acc[c][3] * rd};
    __builtin_nontemporal_store(o, (f32x4*)(orow + c * 64));
  }
}

// -------------------------------------------------------------- launch ----
extern "C" void kernel_launch(void* const* d_in, const int* in_sizes, int n_in,
                              void* d_out, int out_size, void* d_ws, size_t ws_size,
                              hipStream_t stream) {
  const float* x   = (const float*)d_in[0];
  const float* adj = (const float*)d_in[1];
  const float* Wq  = (const float*)d_in[2];
  const float* bq  = (const float*)d_in[3];
  const float* Wk  = (const float*)d_in[4];
  const float* bk  = (const float*)d_in[5];
  const float* Wv  = (const float*)d_in[6];
  const float* bv  = (const float*)d_in[7];
  float* out = (float*)d_out;

  const size_t NX = (size_t)MSEQ * DIM;   // 8,388,608
  const size_t NW = (size_t)DIM * DIM;    // 262,144
  unsigned short* ws = (unsigned short*)d_ws;
  unsigned short* xh  = ws;               // fp16
  unsigned short* wqh = xh + NX;
  unsigned short* wkh = wqh + NW;
  unsigned short* wvh = wkh + NW;
  unsigned short* Qh  = wvh + NW;         // fp16
  unsigned short* Kh  = Qh + NX;          // fp16
  unsigned short* Vt  = Kh + NX;          // bf16, transposed [DIM][MSEQ]

  // 1. fp32 -> fp16 conversions (2 launches)
  cvt_kernel<<<(int)(NX / 4 / 256), 256, 0, stream>>>(x, xh, (int)(NX / 4));
  dim3 cw((int)(NW / 4 / 256), 3);
  cvt_w_kernel<<<cw, 256, 0, stream>>>(Wq, Wk, Wv, wqh, wkh, wvh, (int)(NW / 4));

  // 2. projections (2 launches)
  dim3 pq(DIM / 128, MSEQ / 128, 2);       // (4, 128, 2) — z: Q or K
  proj_qk_kernel<<<pq, 256, 0, stream>>>(xh, wqh, wkh, bq, bk, Qh, Kh);
  dim3 pv(MSEQ / 128, DIM / 128);          // (128, 4)
  proj_v_kernel<<<pv, 256, 0, stream>>>(wvh, xh, bv, Vt);

  // 3. fused attention (scores+agg), 3-buffer counted pipeline, 2 blocks/CU
  attn_kernel<<<512, 512, 0, stream>>>(Qh, Kh, Vt, adj, out);
}

// Round 9
// 612.288 us; speedup vs baseline: 1.0360x; 1.0360x over previous
//
#include <hip/hip_runtime.h>
#include <hip/hip_bf16.h>

// GraphLayer B=8,N=2048,D=512 — Round 13.
//   r12 post-mortem: 224->421us REGRESSION. FETCH 120MB -> 1.156GB: staging
//   adj via global_load_lds (default caching) thrashed the 4MB per-XCD L2
//   and evicted the K/V slabs (r11 used NONTEMPORAL adj loads -> no L2
//   allocation). Also found: with POST-barrier stage issue the correct
//   counted wait is vmcnt(1) (one newer stage), not r12's vmcnt(2/3) which
//   allowed the consumed chunk itself to still be in flight (passed by luck).
//   Changes (attn only; math bit-identical to r9/r11/r12):
//   1) adj: NT scalar loads into 4 REGISTERS, prefetched one tile ahead
//      inside phase-2 step 0 (T14) — epilogue reads regs; sAdj LDS deleted;
//      no L2 pollution, no epilogue latency. LDS 62 -> 53.8KB.
//   2) Waits: vmcnt(1) everywhere; vmcnt(5) only at P2-c1 (stage V2 + 4 adj
//      loads sit between V1 and the wait). Safe under any intra-region
//      instruction order (regions bounded by sched_barrier(0)).
//   Kept from r12: chunk-128 (9 barriers/tile), 3 rotating buffers with
//   post-barrier stage issue, Q in registers, setprio on MFMA clusters,
//   XCD affinity, NT out stores.
// Numerics identical to r9/r11/r12 (passed, absmax 0.0156).

#define BATCH 8
#define SEQ   2048
#define DIM   512
#define MSEQ  (BATCH * SEQ)   // 16384
#define QB    32              // q-rows per attn block
#define KT    64              // k-tile width
#define NTI   (SEQ / KT)      // 32 k-tiles
#define CHK   128             // D-cols per K chunk / d-rows per V chunk

typedef __attribute__((ext_vector_type(8))) short    bf16x8;
typedef __attribute__((ext_vector_type(8))) _Float16 f16x8;
typedef __attribute__((ext_vector_type(4))) float    f32x4;

__device__ __forceinline__ unsigned short f2bf(float f) {
  __hip_bfloat16 h = __float2bfloat16(f);
  union { __hip_bfloat16 h; unsigned short u; } c; c.h = h; return c.u;
}
__device__ __forceinline__ float bf2f(unsigned short u) {
  union { unsigned int u; float f; } c; c.u = ((unsigned int)u) << 16; return c.f;
}
__device__ __forceinline__ unsigned short f2h(float f) {
  union { _Float16 h; unsigned short u; } c; c.h = (_Float16)f; return c.u;
}

__device__ __forceinline__ void async16(const unsigned short* g, unsigned short* l) {
  __builtin_amdgcn_global_load_lds(
      (const __attribute__((address_space(1))) void*)g,
      (__attribute__((address_space(3))) void*)l, 16, 0, 0);
}

// needed chunk was staged 2 steps ago; exactly 1 newer stage may fly
#define WAIT1() asm volatile("s_waitcnt vmcnt(1) lgkmcnt(0)" ::: "memory")
// P2-c1 only: stage V2 + 4 adj NT loads sit between V1 and this wait
#define WAIT5() asm volatile("s_waitcnt vmcnt(5) lgkmcnt(0)" ::: "memory")
#define WAIT_LGKM0() asm volatile("s_waitcnt lgkmcnt(0)" ::: "memory")
// barrier with ACQUIRE fence: post-barrier LDS ops cannot hoist above
#define BAR_ACQ()                                                  \
  do {                                                             \
    __builtin_amdgcn_s_barrier();                                  \
    asm volatile("" ::: "memory");                                 \
    __builtin_amdgcn_sched_barrier(0);                             \
  } while (0)

// ---------------------------------------------------------------- core ----
// acc[i][j] += A[m][k] * B[n][k]  (NT), fp16 MFMA, fp32 acc. 256 threads.
__device__ __forceinline__ void gemm_f16_mainloop(
    const unsigned short* __restrict__ A, const unsigned short* __restrict__ B,
    int lda, int ldb, int K,
    unsigned short* sA, unsigned short* sB, f32x4 acc[4][4])
{
  const int tid  = threadIdx.x;
  const int lane = tid & 63;
  const int w    = tid >> 6;
  const int wm   = w >> 1, wn = w & 1;
  const int quad = lane >> 4, fcol = lane & 15;
  const int srow = lane >> 2;          // 0..15 within a 16-row chunk
  const int gsw  = ((lane & 3) ^ ((srow & 3) ^ ((srow >> 2) & 3))) * 8;
  const int grd  = ((fcol & 3) ^ ((fcol >> 2) & 3));

  for (int k0 = 0; k0 < K; k0 += 32) {
#pragma unroll
    for (int inst = 0; inst < 2; ++inst) {
      const int rbase  = w * 32 + inst * 16;   // wave-uniform
      const int r      = rbase + srow;
      const int ldsoff = rbase * 32;           // row stride 32 ushorts
      async16(A + (size_t)r * lda + k0 + gsw, sA + ldsoff);
      async16(B + (size_t)r * ldb + k0 + gsw, sB + ldsoff);
    }
    __syncthreads();

#pragma unroll
    for (int i = 0; i < 4; ++i) {
      const int ar = wm * 64 + i * 16 + fcol;
      f16x8 a = *(const f16x8*)(sA + ar * 32 + ((quad ^ grd) << 3));
#pragma unroll
      for (int j = 0; j < 4; ++j) {
        const int br = wn * 64 + j * 16 + fcol;
        f16x8 b = *(const f16x8*)(sB + br * 32 + ((quad ^ grd) << 3));
        acc[i][j] = __builtin_amdgcn_mfma_f32_16x16x32_f16(a, b, acc[i][j], 0, 0, 0);
      }
    }
    __syncthreads();
  }
}

#define EPI_SETUP                                                  \
  const int lane = threadIdx.x & 63;                               \
  const int w_   = threadIdx.x >> 6;                               \
  const int wm   = w_ >> 1, wn = w_ & 1;                           \
  const int quad = lane >> 4, fcol = lane & 15;

// ----------------------------------------------------------------- cvt ----
__global__ __launch_bounds__(256) void cvt_kernel(
    const float* __restrict__ in, unsigned short* __restrict__ out, int n4)
{
  int i = blockIdx.x * 256 + threadIdx.x;
  if (i >= n4) return;
  float4 v = ((const float4*)in)[i];
  ushort4 h;
  h.x = f2h(v.x); h.y = f2h(v.y); h.z = f2h(v.z); h.w = f2h(v.w);
  ((ushort4*)out)[i] = h;
}

__global__ __launch_bounds__(256) void cvt_w_kernel(
    const float* __restrict__ w0, const float* __restrict__ w1,
    const float* __restrict__ w2, unsigned short* __restrict__ o0,
    unsigned short* __restrict__ o1, unsigned short* __restrict__ o2, int n4)
{
  int i = blockIdx.x * 256 + threadIdx.x;
  if (i >= n4) return;
  const float* in = (blockIdx.y == 0) ? w0 : (blockIdx.y == 1) ? w1 : w2;
  unsigned short* out = (blockIdx.y == 0) ? o0 : (blockIdx.y == 1) ? o1 : o2;
  float4 v = ((const float4*)in)[i];
  ushort4 h;
  h.x = f2h(v.x); h.y = f2h(v.y); h.z = f2h(v.z); h.w = f2h(v.w);
  ((ushort4*)out)[i] = h;
}

// ------------------------------------------------------------- proj QK ----
__global__ __launch_bounds__(256) void proj_qk_kernel(
    const unsigned short* __restrict__ xh,
    const unsigned short* __restrict__ wq, const unsigned short* __restrict__ wk,
    const float* __restrict__ bq, const float* __restrict__ bk,
    unsigned short* __restrict__ Qh, unsigned short* __restrict__ Kh)
{
  __shared__ unsigned short sA[128 * 32], sB[128 * 32];
  const unsigned short* wh = blockIdx.z ? wk : wq;
  const float* bias        = blockIdx.z ? bk : bq;
  unsigned short* O        = blockIdx.z ? Kh : Qh;
  const int m0 = blockIdx.y * 128, n0 = blockIdx.x * 128;
  f32x4 acc[4][4];
#pragma unroll
  for (int i = 0; i < 4; ++i)
#pragma unroll
    for (int j = 0; j < 4; ++j) acc[i][j] = (f32x4){0.f, 0.f, 0.f, 0.f};

  gemm_f16_mainloop(xh + (size_t)m0 * DIM, wh + (size_t)n0 * DIM,
                    DIM, DIM, DIM, sA, sB, acc);
  EPI_SETUP
#pragma unroll
  for (int i = 0; i < 4; ++i)
#pragma unroll
    for (int j = 0; j < 4; ++j)
#pragma unroll
      for (int r = 0; r < 4; ++r) {
        const int row = m0 + wm * 64 + i * 16 + quad * 4 + r;
        const int col = n0 + wn * 64 + j * 16 + fcol;
        O[(size_t)row * DIM + col] = f2h(acc[i][j][r] + bias[col]);
      }
}

// -------------------------------------------------------------- proj V ----
// Vt[d][m] = Wv[d][:] . x[m][:] + bv[d]   (fp16 in, bf16 out, transposed)
__global__ __launch_bounds__(256) void proj_v_kernel(
    const unsigned short* __restrict__ wvh, const unsigned short* __restrict__ xh,
    const float* __restrict__ bias, unsigned short* __restrict__ Vt)
{
  __shared__ unsigned short sA[128 * 32], sB[128 * 32];
  const int m0 = blockIdx.y * 128, n0 = blockIdx.x * 128;
  f32x4 acc[4][4];
#pragma unroll
  for (int i = 0; i < 4; ++i)
#pragma unroll
    for (int j = 0; j < 4; ++j) acc[i][j] = (f32x4){0.f, 0.f, 0.f, 0.f};

  gemm_f16_mainloop(wvh + (size_t)m0 * DIM, xh + (size_t)n0 * DIM,
                    DIM, DIM, DIM, sA, sB, acc);
  EPI_SETUP
#pragma unroll
  for (int i = 0; i < 4; ++i)
#pragma unroll
    for (int j = 0; j < 4; ++j)
#pragma unroll
      for (int r = 0; r < 4; ++r) {
        const int row = m0 + wm * 64 + i * 16 + quad * 4 + r;   // d
        const int col = n0 + wn * 64 + j * 16 + fcol;           // seq
        Vt[(size_t)row * MSEQ + col] = f2bf(acc[i][j][r] + bias[row]);
      }
}

// ---------------------------------------------------------------- attn ----
// Fused scores+agg; 3-buffer rotating chunk pipeline (post-barrier stage
// issue, vmcnt(1) counted waits); Q in regs; adj NT-prefetched to regs.
// Block: 32 q-rows x D=512, 512 threads (8 waves), 2 blocks/CU.
__global__ __launch_bounds__(512, 4) void attn_kernel(
    const unsigned short* __restrict__ Qh, const unsigned short* __restrict__ Kh,
    const unsigned short* __restrict__ Vt, const float* __restrict__ adj,
    float* __restrict__ out)
{
  // LDS 53760B: Bf[3][8192]us (48KB) | Pb[32][64]us (4KB) | denL[4][32]f32
  __shared__ __align__(16) unsigned short smem[26880];
  unsigned short* Bf   = smem;                    // 3 x 8192 ushorts
  unsigned short* Pb   = smem + 24576;            // row stride 64 ushorts
  float*          denL = (float*)(smem + 26624);  // [4][32]

  const int tid  = threadIdx.x;
  const int lane = tid & 63;
  const int w    = tid >> 6;                    // 0..7
  const int quad = lane >> 4, fcol = lane & 15;
  const int wq = w >> 2, wk = w & 3;            // phase-1 grid 2q x 4k (16x16)
  const int dsub = w >> 1, qsub = w & 1;        // phase-2 grid 4d x 2q (16x16)

  // XCD affinity: round-robin dispatch -> lin%8 = XCD; batch b lives there.
  const int lin = blockIdx.x;                   // 0..511
  const int b   = lin & 7;
  const int q0  = (lin >> 3) * QB;
  const size_t qbase = (size_t)b * SEQ + q0;
  const size_t kbb   = (size_t)b * SEQ;
  const float* adjb  = adj + qbase * SEQ;

  // ---- staging (LDS bases wave-uniform; per-lane global src swizzled)
  // K chunk: [64 k-rows][128 D] fp16 = 16KB; 16 granules/row, XOR row&15.
  auto stage_k = [&](int t, int c, unsigned short* buf) {
#pragma unroll
    for (int rr = 0; rr < 2; ++rr) {
      const int gp  = rr * 512 + tid;
      const int row = gp >> 4, g = gp & 15;
      async16(Kh + (kbb + (size_t)t * KT + row) * DIM + c * CHK + ((g ^ (row & 15)) << 3),
              buf + rr * 4096 + w * 512);
    }
  };
  // V chunk: [128 d-rows][64 k] bf16 = 16KB; 8 granules/row, XOR row&7.
  auto stage_v = [&](int t, int c, unsigned short* buf) {
#pragma unroll
    for (int rr = 0; rr < 2; ++rr) {
      const int gp  = rr * 512 + tid;
      const int row = gp >> 3, g = gp & 7;
      async16(Vt + (size_t)(c * CHK + row) * MSEQ + kbb + (size_t)t * KT + ((g ^ (row & 7)) << 3),
              buf + rr * 4096 + w * 512);
    }
  };

  // ---- Q fragments -> registers (one-time; row = wq*16+fcol, 16 D-slices)
  const int arq = wq * 16 + fcol;
  f16x8 qf[16];
#pragma unroll
  for (int i = 0; i < 16; ++i)
    qf[i] = *(const f16x8*)(Qh + (qbase + arq) * DIM + i * 32 + quad * 8);

  f32x4 acc[8];                                 // out^T: one 16x16 per d-block
#pragma unroll
  for (int c = 0; c < 8; ++c) acc[c] = (f32x4){0.f, 0.f, 0.f, 0.f};
  float den[4] = {0.f, 0.f, 0.f, 0.f};

  // per-thread adj values for the CURRENT tile's epilogue (NT, no L2 alloc)
  const int acol = wk * 16 + fcol;              // epilogue col
  const int arow = wq * 16 + quad * 4;          // epilogue row base
  float adv[4];
#pragma unroll
  for (int r = 0; r < 4; ++r)
    adv[r] = __builtin_nontemporal_load(adjb + (size_t)(arow + r) * SEQ + acol);

  // rotating buffers; prologue: K chunks 0,1 in flight
  unsigned short* p0 = Bf;
  unsigned short* p1 = Bf + 8192;
  unsigned short* p2 = Bf + 16384;
  stage_k(0, 0, p0);
  stage_k(0, 1, p1);

  const int br  = wk * 16 + fcol;               // phase-1 K row
  const int vr0 = dsub * 16 + fcol;             // phase-2 V rows
  const int vr1 = 64 + dsub * 16 + fcol;
  const int qr  = qsub * 16 + fcol;             // phase-2 P q-row

  for (int t = 0; t < NTI; ++t) {
    const int tn = (t + 1 < NTI) ? t + 1 : 0;
    f32x4 sacc = (f32x4){0.f, 0.f, 0.f, 0.f};

    // ---- phase 1: S[32x64] = Q.K^T, 4 steps x 4 MFMAs ------------------
#pragma unroll
    for (int c = 0; c < 4; ++c) {
      WAIT1();             // chunk c (staged 2 steps ago) landed
      BAR_ACQ();
      // stage chunk c+2 into p[(c+2)%3] (buffer drained: last read step c-1)
      if      (c == 0) stage_k(t, 2, p2);
      else if (c == 1) stage_k(t, 3, p0);
      else if (c == 2) stage_v(t, 0, p1);
      else             stage_v(t, 1, p2);
      const unsigned short* Kb = (c == 0) ? p0 : (c == 1) ? p1 : (c == 2) ? p2 : p0;
      __builtin_amdgcn_s_setprio(1);
#pragma unroll
      for (int kw = 0; kw < 4; ++kw) {
        const int G = kw * 4 + quad;
        f16x8 bb = *(const f16x8*)(Kb + br * 128 + ((G ^ (br & 15)) << 3));
        sacc = __builtin_amdgcn_mfma_f32_16x16x32_f16(qf[c * 4 + kw], bb, sacc, 0, 0, 0);
      }
      __builtin_amdgcn_s_setprio(0);
    }

    // ---- epilogue: P = bf16(adv*exp(S)) -> Pb; den += P (adj from regs) -
#pragma unroll
    for (int r = 0; r < 4; ++r) {
      const int row = arow + r;
      const unsigned short pb = f2bf(adv[r] * __expf(sacc[r]));
      Pb[row * 64 + ((((acol >> 3) ^ (row & 7)) << 3) | (acol & 7))] = pb;
      den[r] += bf2f(pb);
    }
    WAIT_LGKM0();          // my P writes committed
    BAR_ACQ();             // all P visible; in-flight DMAs unaffected

    // pa-cache: P fragments once per tile (k-windows 0,1)
    bf16x8 pa0 = *(const bf16x8*)(Pb + qr * 64 + ((quad ^ (qr & 7)) << 3));
    bf16x8 pa1 = *(const bf16x8*)(Pb + qr * 64 + (((4 + quad) ^ (qr & 7)) << 3));

    // ---- phase 2: accT += V.P^T, 4 steps x 4 MFMAs ---------------------
    float advn[4];
#pragma unroll
    for (int c = 0; c < 4; ++c) {
      if (c == 1) { WAIT5(); } else { WAIT1(); }   // c1: V2 + 4 adj after V1
      BAR_ACQ();
      if      (c == 0) {
        stage_v(t, 2, p0);
        // NT prefetch next tile's adj into regs (hidden under ~7 steps)
#pragma unroll
        for (int r = 0; r < 4; ++r)
          advn[r] = __builtin_nontemporal_load(
              adjb + (size_t)(arow + r) * SEQ + (size_t)tn * KT + acol);
      }
      else if (c == 1) stage_v(t, 3, p1);
      else if (c == 2) stage_k(tn, 0, p2);
      else             stage_k(tn, 1, p0);
      const unsigned short* Vb = (c == 0) ? p1 : (c == 1) ? p2 : (c == 2) ? p0 : p1;
      bf16x8 va00 = *(const bf16x8*)(Vb + vr0 * 64 + ((quad ^ (vr0 & 7)) << 3));
      bf16x8 va01 = *(const bf16x8*)(Vb + vr0 * 64 + (((4 + quad) ^ (vr0 & 7)) << 3));
      bf16x8 va10 = *(const bf16x8*)(Vb + vr1 * 64 + ((quad ^ (vr1 & 7)) << 3));
      bf16x8 va11 = *(const bf16x8*)(Vb + vr1 * 64 + (((4 + quad) ^ (vr1 & 7)) << 3));
      __builtin_amdgcn_s_setprio(1);
      acc[2 * c]     = __builtin_amdgcn_mfma_f32_16x16x32_bf16(va00, pa0, acc[2 * c], 0, 0, 0);
      acc[2 * c]     = __builtin_amdgcn_mfma_f32_16x16x32_bf16(va01, pa1, acc[2 * c], 0, 0, 0);
      acc[2 * c + 1] = __builtin_amdgcn_mfma_f32_16x16x32_bf16(va10, pa0, acc[2 * c + 1], 0, 0, 0);
      acc[2 * c + 1] = __builtin_amdgcn_mfma_f32_16x16x32_bf16(va11, pa1, acc[2 * c + 1], 0, 0, 0);
      __builtin_amdgcn_s_setprio(0);
    }
#pragma unroll
    for (int r = 0; r < 4; ++r) adv[r] = advn[r];

    // rotate buffer pointers: chunk counter advances 8 (mod 3 -> +2)
    { unsigned short* tp = p0; p0 = p2; p2 = p1; p1 = tp; }
  }

  // ----------------- den reduce + normalize + store -------------------
#pragma unroll
  for (int r = 0; r < 4; ++r) {
    float v = den[r];
    v += __shfl_xor(v, 1);  v += __shfl_xor(v, 2);
    v += __shfl_xor(v, 4);  v += __shfl_xor(v, 8);
    if (fcol == 0) denL[wk * 32 + wq * 16 + quad * 4 + r] = v;
  }
  __syncthreads();   // full drain + fence fine at kernel end
  const int qloc = qsub * 16 + fcol;
  const float dsum = denL[qloc] + denL[32 + qloc] + denL[64 + qloc] + denL[96 + qloc];
  const float rd = 1.0f / dsum;
  float* orow = out + (qbase + qloc) * DIM + dsub * 16 + quad * 4;
#pragma unroll
  for (int c = 0; c < 8; ++c) {
    f32x4 o = {acc[c][0] * rd, acc[c][1] * rd, acc[c][2] * rd, acc[c][3] * rd};
    __builtin_nontemporal_store(o, (f32x4*)(orow + c * 64));
  }
}

// -------------------------------------------------------------- launch ----
extern "C" void kernel_launch(void* const* d_in, const int* in_sizes, int n_in,
                              void* d_out, int out_size, void* d_ws, size_t ws_size,
                              hipStream_t stream) {
  const float* x   = (const float*)d_in[0];
  const float* adj = (const float*)d_in[1];
  const float* Wq  = (const float*)d_in[2];
  const float* bq  = (const float*)d_in[3];
  const float* Wk  = (const float*)d_in[4];
  const float* bk  = (const float*)d_in[5];
  const float* Wv  = (const float*)d_in[6];
  const float* bv  = (const float*)d_in[7];
  float* out = (float*)d_out;

  const size_t NX = (size_t)MSEQ * DIM;   // 8,388,608
  const size_t NW = (size_t)DIM * DIM;    // 262,144
  unsigned short* ws = (unsigned short*)d_ws;
  unsigned short* xh  = ws;               // fp16
  unsigned short* wqh = xh + NX;
  unsigned short* wkh = wqh + NW;
  unsigned short* wvh = wkh + NW;
  unsigned short* Qh  = wvh + NW;         // fp16
  unsigned short* Kh  = Qh + NX;          // fp16
  unsigned short* Vt  = Kh + NX;          // bf16, transposed [DIM][MSEQ]

  // 1. fp32 -> fp16 conversions (2 launches)
  cvt_kernel<<<(int)(NX / 4 / 256), 256, 0, stream>>>(x, xh, (int)(NX / 4));
  dim3 cw((int)(NW / 4 / 256), 3);
  cvt_w_kernel<<<cw, 256, 0, stream>>>(Wq, Wk, Wv, wqh, wkh, wvh, (int)(NW / 4));

  // 2. projections (2 launches)
  dim3 pq(DIM / 128, MSEQ / 128, 2);       // (4, 128, 2) — z: Q or K
  proj_qk_kernel<<<pq, 256, 0, stream>>>(xh, wqh, wkh, bq, bk, Qh, Kh);
  dim3 pv(MSEQ / 128, DIM / 128);          // (128, 4)
  proj_v_kernel<<<pv, 256, 0, stream>>>(wvh, xh, bv, Vt);

  // 3. fused attention (scores+agg), counted pipeline, 2 blocks/CU
  attn_kernel<<<512, 512, 0, stream>>>(Qh, Kh, Vt, adj, out);
}